// Round 6
// baseline (364.418 us; speedup 1.0000x reference)
//
#include <hip/hip_runtime.h>

typedef __bf16 bf16;
typedef __bf16 v8bf __attribute__((ext_vector_type(8)));
typedef __bf16 v4bf __attribute__((ext_vector_type(4)));
typedef float v4f __attribute__((ext_vector_type(4)));

#define MFMA16(a, b, c) __builtin_amdgcn_mfma_f32_16x16x32_bf16(a, b, c, 0, 0, 0)

// NaN -> 0, clamp +-1e30. Insurance only; fp32 inputs should keep everything finite.
__device__ __forceinline__ float sf(float x) {
  if (!(x == x)) return 0.f;
  return fminf(fmaxf(x, -1e30f), 1e30f);
}

// ---------------- guard fill (fp32 out) ----------------
__global__ __launch_bounds__(256) void fill_kernel(float* __restrict__ out, float v, int n) {
  int i = blockIdx.x * 256 + threadIdx.x;
  if (i < n) out[i] = v;
}

// ---------------- prep: stem weight transpose (fp32->bf16) + BN folding ----------------
// Wt01[which][co][tap][ci] = W[which][co][ci][tap]
__global__ __launch_bounds__(256) void prep_kernel(
    const float* __restrict__ ts_w, const float* __restrict__ tq_w,
    const float* ts_b, const float* ts_g, const float* ts_be, const float* ts_m, const float* ts_v,
    const float* tq_b, const float* tq_g, const float* tq_be, const float* tq_m, const float* tq_v,
    bf16* __restrict__ Wt01, float* __restrict__ ss01)
{
  int idx = blockIdx.x * 256 + threadIdx.x;
  if (idx < 589824) {
    int which = idx / 294912;
    int rem = idx - which * 294912;
    int co = rem / 2304;
    int r2 = rem - co * 2304;
    int tap = r2 >> 8;
    int ci = r2 & 255;
    const float* W = which ? tq_w : ts_w;
    Wt01[idx] = (bf16)W[(co * 256 + ci) * 9 + tap];
  } else if (idx < 590080) {
    int i = idx - 589824;
    int which = i >> 7, c = i & 127;
    float g, be, m, vv, bias;
    if (which == 0) { g=ts_g[c]; be=ts_be[c]; m=ts_m[c]; vv=ts_v[c]; bias=ts_b[c]; }
    else            { g=tq_g[c]; be=tq_be[c]; m=tq_m[c]; vv=tq_v[c]; bias=tq_b[c]; }
    float scale = g / sqrtf(vv + 1e-5f);
    ss01[which * 256 + c] = sf(scale);
    ss01[which * 256 + 128 + c] = sf((bias - m) * scale + be);
  }
}

// ---------------- prep2 (after apply; over dead sfeat): conv_cat weights + BN ----------------
__global__ __launch_bounds__(256) void prep2_kernel(
    const float* __restrict__ cc_w, const float* cc_g, const float* cc_be,
    const float* cc_m, const float* cc_v,
    bf16* __restrict__ Wt2, float* __restrict__ ss_cc)
{
  int idx = blockIdx.x * 256 + threadIdx.x;
  if (idx < 294912) {
    int co = idx / 2304;
    int r2 = idx - co * 2304;
    int tap = r2 >> 8;
    int ci = r2 & 255;
    Wt2[idx] = (bf16)cc_w[(co * 256 + ci) * 9 + tap];
  } else if (idx < 295040) {
    int c = idx - 294912;
    float scale = cc_g[c] / sqrtf(cc_v[c] + 1e-5f);
    ss_cc[c] = sf(scale);
    ss_cc[128 + c] = sf(-cc_m[c] * scale + cc_be[c]);
  }
}

// ---------------- 3x3 conv as implicit GEMM, NCHW fp32 input, boundary-predicated ----------------
// One block per output row y (64 px), all 128 co. mode0: stems (q/s fp32 in) -> NHWC bf16 sfeat.
// mode1: conv_cat (E_q/E_s fp32 from d_out slots 1/2) -> NCHW fp32 d_out slot 0.
__global__ __launch_bounds__(256) void convN_kernel(
    const float* __restrict__ pS, const float* __restrict__ pQ,
    const bf16* __restrict__ Wb, const float* __restrict__ ssb,
    void* __restrict__ out_, int mode)
{
  __shared__ bf16 As[66][40];
  __shared__ bf16 Bs[3][128][40];

  int y = blockIdx.x;
  int z = blockIdx.z;
  int tsr = z >> 1, b = z & 1;

  const float *in0, *in1;
  const bf16* W;
  const float* sp;
  if (mode == 0) {
    const float* base = (tsr ? pQ : pS) + (long)b * 1048576;
    in0 = base; in1 = base + 524288;
    W = Wb + (long)tsr * 294912;
    sp = ssb + tsr * 256;
  } else {
    in0 = pS + 1048576 + (long)b * 524288;   // E_q (fp32 output slot 1)
    in1 = pS + 2097152 + (long)b * 524288;   // E_s (fp32 output slot 2)
    W = Wb; sp = ssb;
  }

  int t = threadIdx.x, lane = t & 63, w = t >> 6;
  int l15 = lane & 15, l4 = lane >> 4;
  int wr = (w & 1) * 32, wc = (w >> 1) * 64;
  int ac = t & 31, ag = t >> 5;
  int bco = t >> 1, bkh = (t & 1) * 16;

  v4f acc[2][4] = {};

  for (int dy = 0; dy < 3; ++dy) {
    int ysrc = y + dy - 1;
    bool yok = (unsigned)ysrc < 64u;
    const bf16* wdy = W + dy * 3 * 256;
    for (int ks = 0; ks < 8; ++ks) {
      int cg = ks * 32 + ac;
      const float* ip = (cg < 128) ? (in0 + (long)cg * 4096) : (in1 + (long)(cg - 128) * 4096);
      float a[8] = {0.f, 0.f, 0.f, 0.f, 0.f, 0.f, 0.f, 0.f};
      if (yok) {
        const float* src = ip + ysrc * 64 + ag * 8;
#pragma unroll
        for (int i = 0; i < 8; ++i) a[i] = src[i];
      }
      const bf16* wk = wdy + (long)bco * 2304 + ks * 32 + bkh;
      v8bf bv0[3], bv1[3];
#pragma unroll
      for (int d = 0; d < 3; ++d) {
        bv0[d] = *(const v8bf*)(wk + d * 256);
        bv1[d] = *(const v8bf*)(wk + d * 256 + 8);
      }
      __syncthreads();
#pragma unroll
      for (int i = 0; i < 8; ++i) As[ag * 8 + 1 + i][ac] = (bf16)a[i];
      if (ag == 0) As[0][ac] = (bf16)0.f;
      if (ag == 7) As[65][ac] = (bf16)0.f;
#pragma unroll
      for (int d = 0; d < 3; ++d) {
        *(v8bf*)&Bs[d][bco][bkh] = bv0[d];
        *(v8bf*)&Bs[d][bco][bkh + 8] = bv1[d];
      }
      __syncthreads();
#pragma unroll
      for (int d = 0; d < 3; ++d) {
        v8bf af0 = *(const v8bf*)&As[wr + d + l15][l4 * 8];
        v8bf af1 = *(const v8bf*)&As[wr + 16 + d + l15][l4 * 8];
#pragma unroll
        for (int j = 0; j < 4; ++j) {
          v8bf bfr = *(const v8bf*)&Bs[d][wc + j * 16 + l15][l4 * 8];
          acc[0][j] = MFMA16(af0, bfr, acc[0][j]);
          acc[1][j] = MFMA16(af1, bfr, acc[1][j]);
        }
      }
    }
  }
#pragma unroll
  for (int i = 0; i < 2; ++i) {
    int nb = y * 64 + wr + i * 16 + l4 * 4;
#pragma unroll
    for (int j = 0; j < 4; ++j) {
      int c = wc + j * 16 + l15;
      float scale = sp[c], shift = sp[128 + c];
      if (mode == 0) {
        bf16* o = (bf16*)out_ + ((long)(tsr * 2 + b) * 4096 + nb) * 128 + c;
#pragma unroll
        for (int r = 0; r < 4; ++r)
          o[r * 128] = (bf16)sf(fmaxf(acc[i][j][r] * scale + shift, 0.f));
      } else {
        v4f pk;
#pragma unroll
        for (int r = 0; r < 4; ++r)
          pk[r] = sf(fmaxf(acc[i][j][r] * scale + shift, 0.f));
        *(v4f*)((float*)out_ + ((long)b * 128 + c) * 4096 + nb) = pk;
      }
    }
  }
}

// ---------------- fused 1x1 convs: [cv | k (br1 negated) | q], fp32 weights ----------------
__global__ __launch_bounds__(256) void conv1_kernel(
    const bf16* __restrict__ feat_base,
    const float* __restrict__ cv_w, const float* __restrict__ k1_w, const float* __restrict__ q1_w,
    const float* __restrict__ k2_w, const float* __restrict__ q2_w,
    const float* __restrict__ cv_b, const float* __restrict__ k1_b, const float* __restrict__ q1_b,
    const float* __restrict__ k2_b, const float* __restrict__ q2_b,
    bf16* __restrict__ v_base, bf16* __restrict__ keyT, bf16* __restrict__ queryT)
{
  int nt = blockIdx.x;
  int br = blockIdx.z >> 1, b = blockIdx.z & 1;
  long zid = br * 2 + b;
  const bf16* feat = feat_base + zid * 524288 + (long)nt * 8192;

  __shared__ bf16 As[64][40];
  __shared__ bf16 Bs[256][40];

  int t = threadIdx.x, lane = t & 63, w = t >> 6;
  int l15 = lane & 15, l4 = lane >> 4;
  int wr = (w & 1) * 32, wc = (w >> 1) * 128;

  const float* wrow;
  bool negk = false;
  if (t < 128)       wrow = cv_w + (long)t * 128;
  else if (t < 192) { wrow = (br ? k2_w : k1_w) + (long)(t - 128) * 128; negk = (br != 0); }
  else               wrow = (br ? q2_w : q1_w) + (long)(t - 192) * 128;

  v4f acc[2][8] = {};
  int ap = t >> 2, ak = (t & 3) * 8;

  for (int ks = 0; ks < 4; ++ks) {
    int ci0 = ks * 32;
    v8bf av = *(const v8bf*)(feat + ap * 128 + ci0 + ak);
    float wv[32];
#pragma unroll
    for (int u = 0; u < 32; ++u) wv[u] = wrow[ci0 + u];
    if (negk) {
#pragma unroll
      for (int u = 0; u < 32; ++u) wv[u] = -wv[u];
    }
    __syncthreads();
    *(v8bf*)&As[ap][ak] = av;
#pragma unroll
    for (int u = 0; u < 32; ++u) Bs[t][u] = (bf16)wv[u];
    __syncthreads();
    v8bf af0 = *(const v8bf*)&As[wr + l15][l4 * 8];
    v8bf af1 = *(const v8bf*)&As[wr + 16 + l15][l4 * 8];
#pragma unroll
    for (int j = 0; j < 8; ++j) {
      v8bf bfr = *(const v8bf*)&Bs[wc + j * 16 + l15][l4 * 8];
      acc[0][j] = MFMA16(af0, bfr, acc[0][j]);
      acc[1][j] = MFMA16(af1, bfr, acc[1][j]);
    }
  }

#pragma unroll
  for (int i = 0; i < 2; ++i) {
    int nb = nt * 64 + wr + i * 16 + l4 * 4;
#pragma unroll
    for (int j = 0; j < 8; ++j) {
      int c = wc + j * 16 + l15;
      float bv;
      if (c < 128)      bv = cv_b[c];
      else if (c < 192) bv = br ? -k2_b[c - 128] : k1_b[c - 128];
      else              bv = (br ? q2_b : q1_b)[c - 192];
      float v0 = sf(acc[i][j][0] + bv), v1 = sf(acc[i][j][1] + bv);
      float v2 = sf(acc[i][j][2] + bv), v3 = sf(acc[i][j][3] + bv);
      if (c < 128) {
        v4bf pk;
        pk[0] = (bf16)v0; pk[1] = (bf16)v1; pk[2] = (bf16)v2; pk[3] = (bf16)v3;
        *(v4bf*)(v_base + zid * 524288 + (long)c * 4096 + nb) = pk;
      } else if (c < 192) {
        int cc = (c - 128) + br * 64;
        bf16* kp = keyT + (long)b * 524288 + (long)nb * 128 + cc;
        kp[0] = (bf16)v0; kp[128] = (bf16)v1; kp[256] = (bf16)v2; kp[384] = (bf16)v3;
      } else {
        int cc = (c - 192) + br * 64;
        bf16* qp = queryT + (long)b * 524288 + (long)nb * 128 + cc;
        qp[0] = (bf16)v0; qp[128] = (bf16)v1; qp[256] = (bf16)v2; qp[384] = (bf16)v3;
      }
    }
  }
}

// ---------------- channel gate: mean over vs + MLP (fp32 gate weights) ----------------
__global__ __launch_bounds__(128) void gate2_kernel(
    const bf16* __restrict__ vs, const float* __restrict__ g1_w, const float* __restrict__ g1_b,
    const float* __restrict__ g2_w, const float* __restrict__ g2_b, float* __restrict__ gate)
{
  __shared__ float p[128];
  __shared__ float h[8];
  int z = blockIdx.x, t = threadIdx.x;
  const bf16* src = vs + (long)z * 524288 + (long)t * 4096;
  float s = 0.f;
  for (int i = 0; i < 4096; i += 8) {
    v8bf v = *(const v8bf*)(src + i);
#pragma unroll
    for (int e = 0; e < 8; ++e) s += (float)v[e];
  }
  p[t] = s * (1.f / 4096.f);
  __syncthreads();
  if (t < 8) {
    float a = g1_b[t];
    for (int c = 0; c < 128; ++c) a += g1_w[t * 128 + c] * p[c];
    h[t] = fmaxf(a, 0.f);
  }
  __syncthreads();
  float a = g2_b[t];
#pragma unroll
  for (int j = 0; j < 8; ++j) a += g2_w[t * 8 + j] * h[j];
  gate[z * 128 + t] = sf(1.f / (1.f + __expf(-a)));
}

// ---------------- flash apply with local row softmax sums -> fp32 d_out slots 1/2 ----------------
__global__ __launch_bounds__(256) void apply_kernel(
    const bf16* __restrict__ keyT, const bf16* __restrict__ queryT,
    const bf16* __restrict__ v_base, const float* __restrict__ gate,
    const bf16* __restrict__ feat_base, float* __restrict__ d_out)
{
  int nt = blockIdx.x, br = blockIdx.z >> 1, b = blockIdx.z & 1;
  int n0 = nt * 64;
  const bf16* X = (br ? queryT : keyT) + ((long)b * 4096 + n0) * 128;
  const bf16* Y = (br ? keyT : queryT) + (long)b * 4096 * 128;
  const bf16* V = v_base + (long)(br * 2 + b) * 524288;
  const float* gt = gate + (br * 2 + b) * 128;
  const bf16* feat = feat_base + (long)(br * 2 + b) * 524288 + (long)n0 * 128;

  __shared__ bf16 Xs[64][136];
  __shared__ bf16 Ys[64][136];
  __shared__ bf16 Vs[128][72];
  __shared__ bf16 Ps[64][72];
  __shared__ float rps[2][64];

  int t = threadIdx.x, lane = t & 63, w = t >> 6;
  int l15 = lane & 15, l4 = lane >> 4;
  int wr = (w & 1) * 32;
  int wm = (w >> 1) * 32;
  int wc = (w >> 1) * 64;

#pragma unroll
  for (int i = 0; i < 4; ++i) {
    int ch = t + i * 256;
    int row = ch >> 4, kk = (ch & 15) * 8;
    *(v8bf*)&Xs[row][kk] = *(const v8bf*)(X + row * 128 + kk);
  }
  __syncthreads();
  v8bf af[2][4];
#pragma unroll
  for (int i = 0; i < 2; ++i)
#pragma unroll
    for (int k = 0; k < 4; ++k)
      af[i][k] = *(const v8bf*)&Xs[wr + i * 16 + l15][k * 32 + l4 * 8];

  v4f acc[2][4] = {};
  float rp[2][4] = {};

  for (int mt = 0; mt < 64; ++mt) {
    int m0 = mt * 64;
    __syncthreads();
#pragma unroll
    for (int i = 0; i < 4; ++i) {
      int ch = t + i * 256;
      int row = ch >> 4, kk = (ch & 15) * 8;
      *(v8bf*)&Ys[row][kk] = *(const v8bf*)(Y + (long)(m0 + row) * 128 + kk);
      int c = ch >> 3, mm = (ch & 7) * 8;
      *(v8bf*)&Vs[c][mm] = *(const v8bf*)(V + (long)c * 4096 + m0 + mm);
    }
    __syncthreads();
    v4f sacc[2][2] = {};
#pragma unroll
    for (int k = 0; k < 4; ++k) {
      v8bf b0 = *(const v8bf*)&Ys[wm + l15][k * 32 + l4 * 8];
      v8bf b1 = *(const v8bf*)&Ys[wm + 16 + l15][k * 32 + l4 * 8];
      sacc[0][0] = MFMA16(af[0][k], b0, sacc[0][0]);
      sacc[0][1] = MFMA16(af[0][k], b1, sacc[0][1]);
      sacc[1][0] = MFMA16(af[1][k], b0, sacc[1][0]);
      sacc[1][1] = MFMA16(af[1][k], b1, sacc[1][1]);
    }
#pragma unroll
    for (int i = 0; i < 2; ++i)
#pragma unroll
      for (int j = 0; j < 2; ++j)
#pragma unroll
        for (int r = 0; r < 4; ++r) {
          float e = __expf(fminf(fabsf(sacc[i][j][r]), 80.f) - 50.f);
          e = sf(e);
          rp[i][r] += e;
          Ps[wr + i * 16 + l4 * 4 + r][wm + j * 16 + l15] = (bf16)e;
        }
    __syncthreads();
#pragma unroll
    for (int k = 0; k < 2; ++k) {
      v8bf p0 = *(const v8bf*)&Ps[wr + l15][k * 32 + l4 * 8];
      v8bf p1 = *(const v8bf*)&Ps[wr + 16 + l15][k * 32 + l4 * 8];
#pragma unroll
      for (int j = 0; j < 4; ++j) {
        v8bf vb = *(const v8bf*)&Vs[wc + j * 16 + l15][k * 32 + l4 * 8];
        acc[0][j] = MFMA16(p0, vb, acc[0][j]);
        acc[1][j] = MFMA16(p1, vb, acc[1][j]);
      }
    }
  }
#pragma unroll
  for (int i = 0; i < 2; ++i)
#pragma unroll
    for (int r = 0; r < 4; ++r) {
      float v = rp[i][r];
      v += __shfl_xor(v, 1, 64);
      v += __shfl_xor(v, 2, 64);
      v += __shfl_xor(v, 4, 64);
      v += __shfl_xor(v, 8, 64);
      rp[i][r] = v;
    }
  __syncthreads();
  if (l15 == 0) {
#pragma unroll
    for (int i = 0; i < 2; ++i)
#pragma unroll
      for (int r = 0; r < 4; ++r)
        rps[w >> 1][wr + i * 16 + l4 * 4 + r] = rp[i][r];
  }
  __syncthreads();

  // E_q -> fp32 output slot 1, E_s -> fp32 output slot 2
  float* outE = d_out + (long)(br ? 1 : 2) * 1048576 + (long)b * 524288;
#pragma unroll
  for (int i = 0; i < 2; ++i) {
    int rowt = wr + i * 16 + l4 * 4;
    float dv[4];
#pragma unroll
    for (int r = 0; r < 4; ++r) dv[r] = fmaxf(rps[0][rowt + r] + rps[1][rowt + r], 1e-30f);
#pragma unroll
    for (int j = 0; j < 4; ++j) {
      int c = wc + j * 16 + l15;
      float g = gt[c];
      v4f pk;
#pragma unroll
      for (int r = 0; r < 4; ++r) {
        float val = acc[i][j][r] / dv[r] * g + (float)feat[(long)(rowt + r) * 128 + c];
        pk[r] = sf(val);
      }
      *(v4f*)(outE + (long)c * 4096 + n0 + rowt) = pk;
    }
  }
}

// ---------------- launch ----------------
extern "C" void kernel_launch(void* const* d_in, const int* in_sizes, int n_in,
                              void* d_out, int out_size, void* d_ws, size_t ws_size,
                              hipStream_t stream)
{
  // interface guard: distinct signal
  if (n_in != 33 || in_sizes[0] != 2097152 || in_sizes[2] != 294912 ||
      in_sizes[14] != 16384 || out_size != 3145728) {
    fill_kernel<<<12288, 256, 0, stream>>>((float*)d_out, 100.0f, 3145728);
    return;
  }
  // ws guard: distinct signal
  if (ws_size < 12582912) {
    fill_kernel<<<12288, 256, 0, stream>>>((float*)d_out, 1.0f, 3145728);
    return;
  }

  const float* q_in = (const float*)d_in[0];
  const float* s_in = (const float*)d_in[1];
  float* outf = (float*)d_out;

  // d_out slot-0 scratch: gate only (2 KB fp32), overwritten by cpam at the end
  float* gate = outf;  // [4][128] f32

  char* ws = (char*)d_ws;
  bf16*  sfeat  = (bf16*)(ws + 0);         // [4][4096][128] bf16
  bf16*  vs     = (bf16*)(ws + 4194304);   // [4][128][4096] bf16
  bf16*  keyT   = (bf16*)(ws + 8388608);   // [2][4096][128] bf16
  bf16*  queryT = (bf16*)(ws + 10485760);  // [2][4096][128] bf16
  bf16*  Wt01   = (bf16*)(ws + 8388608);   // alias: dead before conv1 writes keyT
  float* ss01   = (float*)(ws + 10485760); // alias: dead before conv1 writes queryT
  bf16*  Wt2    = (bf16*)(ws + 0);         // alias over dead sfeat (after apply)
  float* ss_cc  = (float*)(ws + 589824);

  prep_kernel<<<2306, 256, 0, stream>>>(
      (const float*)d_in[2], (const float*)d_in[8],
      (const float*)d_in[3], (const float*)d_in[4], (const float*)d_in[5],
      (const float*)d_in[6], (const float*)d_in[7],
      (const float*)d_in[9], (const float*)d_in[10], (const float*)d_in[11],
      (const float*)d_in[12], (const float*)d_in[13],
      Wt01, ss01);

  // stems: z = tsr*2+b (tsr0 = s/ts, tsr1 = q/tq) -> sfeat NHWC bf16
  convN_kernel<<<dim3(64, 1, 4), 256, 0, stream>>>(s_in, q_in, Wt01, ss01, sfeat, 0);

  conv1_kernel<<<dim3(64, 1, 4), 256, 0, stream>>>(
      sfeat,
      (const float*)d_in[14], (const float*)d_in[16], (const float*)d_in[18],
      (const float*)d_in[20], (const float*)d_in[22],
      (const float*)d_in[15], (const float*)d_in[17], (const float*)d_in[19],
      (const float*)d_in[21], (const float*)d_in[23],
      vs, keyT, queryT);

  gate2_kernel<<<4, 128, 0, stream>>>(vs, (const float*)d_in[24], (const float*)d_in[25],
                                      (const float*)d_in[26], (const float*)d_in[27], gate);

  apply_kernel<<<dim3(64, 1, 4), 256, 0, stream>>>(keyT, queryT, vs, gate, sfeat, outf);

  prep2_kernel<<<1153, 256, 0, stream>>>(
      (const float*)d_in[28], (const float*)d_in[29], (const float*)d_in[30],
      (const float*)d_in[31], (const float*)d_in[32], Wt2, ss_cc);

  // conv_cat: reads E_q/E_s fp32 from d_out slots 1/2, writes cpam fp32 to slot 0 (NCHW)
  convN_kernel<<<dim3(64, 1, 2), 256, 0, stream>>>(outf, nullptr, Wt2, ss_cc, outf, 1);
}

// Round 8
// 300.305 us; speedup vs baseline: 1.2135x; 1.2135x over previous
//
#include <hip/hip_runtime.h>

typedef __bf16 bf16;
typedef __bf16 v8bf __attribute__((ext_vector_type(8)));
typedef __bf16 v4bf __attribute__((ext_vector_type(4)));
typedef float v4f __attribute__((ext_vector_type(4)));

#define MFMA16(a, b, c) __builtin_amdgcn_mfma_f32_16x16x32_bf16(a, b, c, 0, 0, 0)

// NaN -> 0, clamp +-1e30. Insurance only.
__device__ __forceinline__ float sf(float x) {
  if (!(x == x)) return 0.f;
  return fminf(fmaxf(x, -1e30f), 1e30f);
}

// ---------------- guard fill (fp32 out) ----------------
__global__ __launch_bounds__(256) void fill_kernel(float* __restrict__ out, float v, int n) {
  int i = blockIdx.x * 256 + threadIdx.x;
  if (i < n) out[i] = v;
}

// ---------------- prep: stem weight transpose (fp32->bf16) + BN folding ----------------
__global__ __launch_bounds__(256) void prep_kernel(
    const float* __restrict__ ts_w, const float* __restrict__ tq_w,
    const float* ts_b, const float* ts_g, const float* ts_be, const float* ts_m, const float* ts_v,
    const float* tq_b, const float* tq_g, const float* tq_be, const float* tq_m, const float* tq_v,
    bf16* __restrict__ Wt01, float* __restrict__ ss01)
{
  int idx = blockIdx.x * 256 + threadIdx.x;
  if (idx < 589824) {
    int which = idx / 294912;
    int rem = idx - which * 294912;
    int co = rem / 2304;
    int r2 = rem - co * 2304;
    int tap = r2 >> 8;
    int ci = r2 & 255;
    const float* W = which ? tq_w : ts_w;
    Wt01[idx] = (bf16)W[(co * 256 + ci) * 9 + tap];
  } else if (idx < 590080) {
    int i = idx - 589824;
    int which = i >> 7, c = i & 127;
    float g, be, m, vv, bias;
    if (which == 0) { g=ts_g[c]; be=ts_be[c]; m=ts_m[c]; vv=ts_v[c]; bias=ts_b[c]; }
    else            { g=tq_g[c]; be=tq_be[c]; m=tq_m[c]; vv=tq_v[c]; bias=tq_b[c]; }
    float scale = g / sqrtf(vv + 1e-5f);
    ss01[which * 256 + c] = sf(scale);
    ss01[which * 256 + 128 + c] = sf((bias - m) * scale + be);
  }
}

// ---------------- prep2 (after apply; over dead sfeat): conv_cat weights + BN ----------------
__global__ __launch_bounds__(256) void prep2_kernel(
    const float* __restrict__ cc_w, const float* cc_g, const float* cc_be,
    const float* cc_m, const float* cc_v,
    bf16* __restrict__ Wt2, float* __restrict__ ss_cc)
{
  int idx = blockIdx.x * 256 + threadIdx.x;
  if (idx < 294912) {
    int co = idx / 2304;
    int r2 = idx - co * 2304;
    int tap = r2 >> 8;
    int ci = r2 & 255;
    Wt2[idx] = (bf16)cc_w[(co * 256 + ci) * 9 + tap];
  } else if (idx < 295040) {
    int c = idx - 294912;
    float scale = cc_g[c] / sqrtf(cc_v[c] + 1e-5f);
    ss_cc[c] = sf(scale);
    ss_cc[128 + c] = sf(-cc_m[c] * scale + cc_be[c]);
  }
}

// ---------------- 3x3 conv implicit GEMM, co-split (blockIdx.y), reg-prefetch pipeline ----------
__global__ __launch_bounds__(256) void convN_kernel(
    const float* __restrict__ pS, const float* __restrict__ pQ,
    const bf16* __restrict__ Wb, const float* __restrict__ ssb,
    void* __restrict__ out_, int mode)
{
  __shared__ bf16 As[66][40];
  __shared__ bf16 Bs[3][64][40];

  int y = blockIdx.x;
  int co0 = blockIdx.y * 64;
  int z = blockIdx.z;
  int tsr = z >> 1, b = z & 1;

  const float *in0, *in1;
  const bf16* W;
  const float* sp;
  if (mode == 0) {
    const float* base = (tsr ? pQ : pS) + (long)b * 1048576;
    in0 = base; in1 = base + 524288;
    W = Wb + (long)tsr * 294912;
    sp = ssb + tsr * 256;
  } else {
    in0 = pS + 1048576 + (long)b * 524288;   // E_q (fp32 output slot 1)
    in1 = pS + 2097152 + (long)b * 524288;   // E_s (fp32 output slot 2)
    W = Wb; sp = ssb;
  }

  int t = threadIdx.x, lane = t & 63, w = t >> 6;
  int l15 = lane & 15, l4 = lane >> 4;
  int wr = (w & 1) * 32, wc = (w >> 1) * 32;
  int ac = t & 31, ag = t >> 5;
  int bco = t >> 2, bk = (t & 3) * 8;

  v4f acc[2][2] = {};

  auto loadA = [&](int it, v8bf& areg) {
    int dy = it >> 3, ks = it & 7;
    int ysrc = y + dy - 1;
    int cg = ks * 32 + ac;
    const float* ip = (cg < 128) ? (in0 + (long)cg * 4096) : (in1 + (long)(cg - 128) * 4096);
    if ((unsigned)ysrc < 64u) {
      const float* src = ip + ysrc * 64 + ag * 8;
#pragma unroll
      for (int i = 0; i < 8; ++i) areg[i] = (bf16)src[i];
    } else {
#pragma unroll
      for (int i = 0; i < 8; ++i) areg[i] = (bf16)0.f;
    }
  };
  auto loadB = [&](int it, v8bf* breg) {
    int dy = it >> 3, ks = it & 7;
    const bf16* wk = W + (long)(co0 + bco) * 2304 + dy * 3 * 256 + ks * 32 + bk;
#pragma unroll
    for (int d = 0; d < 3; ++d) breg[d] = *(const v8bf*)(wk + d * 256);
  };

  v8bf areg, breg[3];
  loadA(0, areg);
  loadB(0, breg);

  for (int it = 0; it < 24; ++it) {
    __syncthreads();
#pragma unroll
    for (int i = 0; i < 8; ++i) As[ag * 8 + 1 + i][ac] = areg[i];
    if (ag == 0) As[0][ac] = (bf16)0.f;
    if (ag == 7) As[65][ac] = (bf16)0.f;
#pragma unroll
    for (int d = 0; d < 3; ++d) *(v8bf*)&Bs[d][bco][bk] = breg[d];
    __syncthreads();
    if (it < 23) { loadA(it + 1, areg); loadB(it + 1, breg); }
#pragma unroll
    for (int d = 0; d < 3; ++d) {
      v8bf af0 = *(const v8bf*)&As[wr + d + l15][l4 * 8];
      v8bf af1 = *(const v8bf*)&As[wr + 16 + d + l15][l4 * 8];
#pragma unroll
      for (int j = 0; j < 2; ++j) {
        v8bf bfr = *(const v8bf*)&Bs[d][wc + j * 16 + l15][l4 * 8];
        acc[0][j] = MFMA16(af0, bfr, acc[0][j]);
        acc[1][j] = MFMA16(af1, bfr, acc[1][j]);
      }
    }
  }
#pragma unroll
  for (int i = 0; i < 2; ++i) {
    int nb = y * 64 + wr + i * 16 + l4 * 4;
#pragma unroll
    for (int j = 0; j < 2; ++j) {
      int c = co0 + wc + j * 16 + l15;
      float scale = sp[c], shift = sp[128 + c];
      if (mode == 0) {
        bf16* o = (bf16*)out_ + ((long)(tsr * 2 + b) * 4096 + nb) * 128 + c;
#pragma unroll
        for (int r = 0; r < 4; ++r)
          o[r * 128] = (bf16)sf(fmaxf(acc[i][j][r] * scale + shift, 0.f));
      } else {
        v4f pk;
#pragma unroll
        for (int r = 0; r < 4; ++r)
          pk[r] = sf(fmaxf(acc[i][j][r] * scale + shift, 0.f));
        *(v4f*)((float*)out_ + ((long)b * 128 + c) * 4096 + nb) = pk;
      }
    }
  }
}

// ---------------- fused 1x1 convs (row-split, 32 rows/block), NO atomics ----------------
__global__ __launch_bounds__(256) void conv1_kernel(
    const bf16* __restrict__ feat_base,
    const float* __restrict__ cv_w, const float* __restrict__ k1_w, const float* __restrict__ q1_w,
    const float* __restrict__ k2_w, const float* __restrict__ q2_w,
    const float* __restrict__ cv_b, const float* __restrict__ k1_b, const float* __restrict__ q1_b,
    const float* __restrict__ k2_b, const float* __restrict__ q2_b,
    bf16* __restrict__ v_base, bf16* __restrict__ keyT, bf16* __restrict__ queryT)
{
  int nt = blockIdx.x;  // 0..127, 32 rows each
  int br = blockIdx.z >> 1, b = blockIdx.z & 1;
  long zid = br * 2 + b;
  const bf16* feat = feat_base + zid * 524288 + (long)nt * 4096;

  __shared__ bf16 As[32][40];
  __shared__ bf16 Bs[256][40];

  int t = threadIdx.x, lane = t & 63, w = t >> 6;
  int l15 = lane & 15, l4 = lane >> 4;
  int wr = (w & 1) * 16, wc = (w >> 1) * 128;

  const float* wrow;
  bool negk = false;
  if (t < 128)       wrow = cv_w + (long)t * 128;
  else if (t < 192) { wrow = (br ? k2_w : k1_w) + (long)(t - 128) * 128; negk = (br != 0); }
  else               wrow = (br ? q2_w : q1_w) + (long)(t - 192) * 128;

  v4f acc[8] = {};
  int ap = t >> 2, ak = (t & 3) * 8;

  for (int ks = 0; ks < 4; ++ks) {
    int ci0 = ks * 32;
    v8bf av;
    if (t < 128) av = *(const v8bf*)(feat + ap * 128 + ci0 + ak);
    float wv[32];
#pragma unroll
    for (int u = 0; u < 32; ++u) wv[u] = wrow[ci0 + u];
    if (negk) {
#pragma unroll
      for (int u = 0; u < 32; ++u) wv[u] = -wv[u];
    }
    __syncthreads();
    if (t < 128) *(v8bf*)&As[ap][ak] = av;
#pragma unroll
    for (int u = 0; u < 32; ++u) Bs[t][u] = (bf16)wv[u];
    __syncthreads();
    v8bf af = *(const v8bf*)&As[wr + l15][l4 * 8];
#pragma unroll
    for (int j = 0; j < 8; ++j) {
      v8bf bfr = *(const v8bf*)&Bs[wc + j * 16 + l15][l4 * 8];
      acc[j] = MFMA16(af, bfr, acc[j]);
    }
  }

  int nb = nt * 32 + wr + l4 * 4;
#pragma unroll
  for (int j = 0; j < 8; ++j) {
    int c = wc + j * 16 + l15;
    float bv;
    if (c < 128)      bv = cv_b[c];
    else if (c < 192) bv = br ? -k2_b[c - 128] : k1_b[c - 128];
    else              bv = (br ? q2_b : q1_b)[c - 192];
    float v0 = sf(acc[j][0] + bv), v1 = sf(acc[j][1] + bv);
    float v2 = sf(acc[j][2] + bv), v3 = sf(acc[j][3] + bv);
    if (c < 128) {
      v4bf pk;
      pk[0] = (bf16)v0; pk[1] = (bf16)v1; pk[2] = (bf16)v2; pk[3] = (bf16)v3;
      *(v4bf*)(v_base + zid * 524288 + (long)c * 4096 + nb) = pk;
    } else if (c < 192) {
      int cc = (c - 128) + br * 64;
      bf16* kp = keyT + (long)b * 524288 + (long)nb * 128 + cc;
      kp[0] = (bf16)v0; kp[128] = (bf16)v1; kp[256] = (bf16)v2; kp[384] = (bf16)v3;
    } else {
      int cc = (c - 192) + br * 64;
      bf16* qp = queryT + (long)b * 524288 + (long)nb * 128 + cc;
      qp[0] = (bf16)v0; qp[128] = (bf16)v1; qp[256] = (bf16)v2; qp[384] = (bf16)v3;
    }
  }
}

// ---------------- gate means: one wave per (image, channel), plain stores ----------------
__global__ __launch_bounds__(64) void pmean_kernel(
    const bf16* __restrict__ vs, float* __restrict__ pmean)
{
  int c = blockIdx.x, z = blockIdx.y, l = threadIdx.x;
  const bf16* src = vs + ((long)z * 128 + c) * 4096;
  float s = 0.f;
#pragma unroll
  for (int k = 0; k < 8; ++k) {
    v8bf v = *(const v8bf*)(src + k * 512 + l * 8);
#pragma unroll
    for (int e = 0; e < 8; ++e) s += (float)v[e];
  }
  s += __shfl_xor(s, 1, 64);
  s += __shfl_xor(s, 2, 64);
  s += __shfl_xor(s, 4, 64);
  s += __shfl_xor(s, 8, 64);
  s += __shfl_xor(s, 16, 64);
  s += __shfl_xor(s, 32, 64);
  if (l == 0) pmean[z * 128 + c] = s * (1.f / 4096.f);
}

// ---------------- channel gate MLP (tiny; reads pmean) ----------------
__global__ __launch_bounds__(128) void gate2_kernel(
    const float* __restrict__ pmean, const float* __restrict__ g1_w, const float* __restrict__ g1_b,
    const float* __restrict__ g2_w, const float* __restrict__ g2_b, float* __restrict__ gate)
{
  __shared__ float p[128];
  __shared__ float h[8];
  int z = blockIdx.x, t = threadIdx.x;
  p[t] = pmean[z * 128 + t];
  __syncthreads();
  if (t < 8) {
    float a = g1_b[t];
    for (int c = 0; c < 128; ++c) a += g1_w[t * 128 + c] * p[c];
    h[t] = fmaxf(a, 0.f);
  }
  __syncthreads();
  float a = g2_b[t];
#pragma unroll
  for (int j = 0; j < 8; ++j) a += g2_w[t * 8 + j] * h[j];
  gate[z * 128 + t] = sf(1.f / (1.f + __expf(-a)));
}

// ---------------- flash apply v2: QK col-split, reg double-buffer, local row sums ----------------
__global__ __launch_bounds__(256) void apply_kernel(
    const bf16* __restrict__ keyT, const bf16* __restrict__ queryT,
    const bf16* __restrict__ v_base, const float* __restrict__ gate,
    const bf16* __restrict__ feat_base, float* __restrict__ d_out)
{
  int nt = blockIdx.x, br = blockIdx.z >> 1, b = blockIdx.z & 1;
  int n0 = nt * 64;
  const bf16* X = (br ? queryT : keyT) + ((long)b * 4096 + n0) * 128;
  const bf16* Y = (br ? keyT : queryT) + (long)b * 4096 * 128;
  const bf16* V = v_base + (long)(br * 2 + b) * 524288;
  const float* gt = gate + (br * 2 + b) * 128;
  const bf16* feat = feat_base + (long)(br * 2 + b) * 524288 + (long)n0 * 128;

  __shared__ bf16 Ys[64][132];
  __shared__ bf16 Vs[128][68];
  __shared__ bf16 Ps[64][68];
  __shared__ float rps[4][64];

  int t = threadIdx.x, lane = t & 63, w = t >> 6;
  int l15 = lane & 15, l4 = lane >> 4;
  int wm = w * 16;           // QK: wave's 16 S-columns
  int wr = (w & 1) * 32;     // PV/epilogue mapping
  int wc = (w >> 1) * 64;

#pragma unroll
  for (int i = 0; i < 4; ++i) {
    int ch = t + i * 256;
    *(v8bf*)&Ys[ch >> 4][(ch & 15) * 8] = *(const v8bf*)(X + (ch >> 4) * 128 + (ch & 15) * 8);
  }
  __syncthreads();
  v8bf af[4][4];
#pragma unroll
  for (int i = 0; i < 4; ++i)
#pragma unroll
    for (int k = 0; k < 4; ++k)
      af[i][k] = *(const v8bf*)&Ys[i * 16 + l15][k * 32 + l4 * 8];

  v4f acc[2][4] = {};
  float rp[4][4] = {};

  v8bf yreg[4], vreg[4];
#pragma unroll
  for (int i = 0; i < 4; ++i) {
    int ch = t + i * 256;
    yreg[i] = *(const v8bf*)(Y + (long)(ch >> 4) * 128 + (ch & 15) * 8);
    vreg[i] = *(const v8bf*)(V + (long)(ch >> 3) * 4096 + (ch & 7) * 8);
  }

  for (int mt = 0; mt < 64; ++mt) {
    __syncthreads();
#pragma unroll
    for (int i = 0; i < 4; ++i) {
      int ch = t + i * 256;
      *(v8bf*)&Ys[ch >> 4][(ch & 15) * 8] = yreg[i];
      *(v8bf*)&Vs[ch >> 3][(ch & 7) * 8] = vreg[i];
    }
    __syncthreads();
    if (mt < 63) {
      int m0 = (mt + 1) * 64;
#pragma unroll
      for (int i = 0; i < 4; ++i) {
        int ch = t + i * 256;
        yreg[i] = *(const v8bf*)(Y + (long)(m0 + (ch >> 4)) * 128 + (ch & 15) * 8);
        vreg[i] = *(const v8bf*)(V + (long)(ch >> 3) * 4096 + m0 + (ch & 7) * 8);
      }
    }
    v4f sacc[4] = {};
#pragma unroll
    for (int k = 0; k < 4; ++k) {
      v8bf by = *(const v8bf*)&Ys[wm + l15][k * 32 + l4 * 8];
#pragma unroll
      for (int i = 0; i < 4; ++i)
        sacc[i] = MFMA16(af[i][k], by, sacc[i]);
    }
#pragma unroll
    for (int i = 0; i < 4; ++i)
#pragma unroll
      for (int r = 0; r < 4; ++r) {
        float e = __expf(fminf(fabsf(sacc[i][r]), 80.f) - 50.f);
        rp[i][r] += e;
        Ps[i * 16 + l4 * 4 + r][wm + l15] = (bf16)e;
      }
    __syncthreads();
#pragma unroll
    for (int k = 0; k < 2; ++k) {
      v8bf p0 = *(const v8bf*)&Ps[wr + l15][k * 32 + l4 * 8];
      v8bf p1 = *(const v8bf*)&Ps[wr + 16 + l15][k * 32 + l4 * 8];
#pragma unroll
      for (int j = 0; j < 4; ++j) {
        v8bf vb = *(const v8bf*)&Vs[wc + j * 16 + l15][k * 32 + l4 * 8];
        acc[0][j] = MFMA16(p0, vb, acc[0][j]);
        acc[1][j] = MFMA16(p1, vb, acc[1][j]);
      }
    }
  }
#pragma unroll
  for (int i = 0; i < 4; ++i)
#pragma unroll
    for (int r = 0; r < 4; ++r) {
      float v = rp[i][r];
      v += __shfl_xor(v, 1, 64);
      v += __shfl_xor(v, 2, 64);
      v += __shfl_xor(v, 4, 64);
      v += __shfl_xor(v, 8, 64);
      if (l15 == 0) rps[w][i * 16 + l4 * 4 + r] = v;
    }
  __syncthreads();

  float* outE = d_out + (long)(br ? 1 : 2) * 1048576 + (long)b * 524288;
#pragma unroll
  for (int i = 0; i < 2; ++i) {
    int rowt = wr + i * 16 + l4 * 4;
    float dv[4];
#pragma unroll
    for (int r = 0; r < 4; ++r)
      dv[r] = fmaxf(rps[0][rowt + r] + rps[1][rowt + r] + rps[2][rowt + r] + rps[3][rowt + r],
                    1e-30f);
#pragma unroll
    for (int j = 0; j < 4; ++j) {
      int c = wc + j * 16 + l15;
      float g = gt[c];
      v4f pk;
#pragma unroll
      for (int r = 0; r < 4; ++r) {
        float val = acc[i][j][r] / dv[r] * g + (float)feat[(long)(rowt + r) * 128 + c];
        pk[r] = sf(val);
      }
      *(v4f*)(outE + (long)c * 4096 + n0 + rowt) = pk;
    }
  }
}

// ---------------- launch ----------------
extern "C" void kernel_launch(void* const* d_in, const int* in_sizes, int n_in,
                              void* d_out, int out_size, void* d_ws, size_t ws_size,
                              hipStream_t stream)
{
  if (n_in != 33 || in_sizes[0] != 2097152 || in_sizes[2] != 294912 ||
      in_sizes[14] != 16384 || out_size != 3145728) {
    fill_kernel<<<12288, 256, 0, stream>>>((float*)d_out, 100.0f, 3145728);
    return;
  }
  if (ws_size < 12582912) {
    fill_kernel<<<12288, 256, 0, stream>>>((float*)d_out, 1.0f, 3145728);
    return;
  }

  const float* q_in = (const float*)d_in[0];
  const float* s_in = (const float*)d_in[1];
  char* ob = (char*)d_out;
  float* outf = (float*)d_out;

  // d_out slot-0 scratch (first 4 KB), plain writes only, overwritten by cpam at the end
  float* gate  = (float*)(ob + 0);     // [4][128] f32
  float* pmean = (float*)(ob + 2048);  // [4][128] f32

  char* ws = (char*)d_ws;
  bf16*  sfeat  = (bf16*)(ws + 0);         // [4][4096][128] bf16
  bf16*  vs     = (bf16*)(ws + 4194304);   // [4][128][4096] bf16
  bf16*  keyT   = (bf16*)(ws + 8388608);   // [2][4096][128] bf16
  bf16*  queryT = (bf16*)(ws + 10485760);  // [2][4096][128] bf16
  bf16*  Wt01   = (bf16*)(ws + 8388608);   // alias: dead before conv1 writes keyT
  float* ss01   = (float*)(ws + 10485760); // alias: dead before conv1 writes queryT
  bf16*  Wt2    = (bf16*)(ws + 0);         // alias over dead sfeat (after apply)
  float* ss_cc  = (float*)(ws + 589824);

  prep_kernel<<<2306, 256, 0, stream>>>(
      (const float*)d_in[2], (const float*)d_in[8],
      (const float*)d_in[3], (const float*)d_in[4], (const float*)d_in[5],
      (const float*)d_in[6], (const float*)d_in[7],
      (const float*)d_in[9], (const float*)d_in[10], (const float*)d_in[11],
      (const float*)d_in[12], (const float*)d_in[13],
      Wt01, ss01);

  convN_kernel<<<dim3(64, 2, 4), 256, 0, stream>>>(s_in, q_in, Wt01, ss01, sfeat, 0);

  conv1_kernel<<<dim3(128, 1, 4), 256, 0, stream>>>(
      sfeat,
      (const float*)d_in[14], (const float*)d_in[16], (const float*)d_in[18],
      (const float*)d_in[20], (const float*)d_in[22],
      (const float*)d_in[15], (const float*)d_in[17], (const float*)d_in[19],
      (const float*)d_in[21], (const float*)d_in[23],
      vs, keyT, queryT);

  pmean_kernel<<<dim3(128, 4), 64, 0, stream>>>(vs, pmean);

  gate2_kernel<<<4, 128, 0, stream>>>(pmean, (const float*)d_in[24], (const float*)d_in[25],
                                      (const float*)d_in[26], (const float*)d_in[27], gate);

  apply_kernel<<<dim3(64, 1, 4), 256, 0, stream>>>(keyT, queryT, vs, gate, sfeat, outf);

  prep2_kernel<<<1153, 256, 0, stream>>>(
      (const float*)d_in[28], (const float*)d_in[29], (const float*)d_in[30],
      (const float*)d_in[31], (const float*)d_in[32], Wt2, ss_cc);

  convN_kernel<<<dim3(64, 2, 2), 256, 0, stream>>>(outf, nullptr, Wt2, ss_cc, outf, 1);
}